// Round 1
// baseline (141.222 us; speedup 1.0000x reference)
//
#include <hip/hip_runtime.h>

// Problem constants (match reference)
#define IMG_H 512
#define IMG_W 512
#define KH 32
#define KW 32
#define SH 16
#define SW 16
#define PH 8
#define PW 8
#define NKH 32
#define NKW 32
#define NK (NKH * NKW)      // 1024 output positions
#define BATCH 64
#define TB 16               // batches per block (4 per wave)

// One block = 256 threads = 4 waves. blockIdx.x = position n, blockIdx.y = batch group.
// Each wave computes the full 1024-element dot for 4 batches at position n.
// Weights: 16 floats per lane in registers (k = 256*j + 4*lane + e), loaded once.
__global__ __launch_bounds__(256)
void bslc_kernel(const float* __restrict__ x,
                 const float* __restrict__ w,
                 const float* __restrict__ bias,
                 float* __restrict__ out)
{
    const int n    = blockIdx.x;        // 0..1023
    const int nr   = n >> 5;
    const int nc   = n & 31;
    const int b0   = blockIdx.y * TB;
    const int lane = threadIdx.x & 63;
    const int wv   = threadIdx.x >> 6;  // wave id 0..3

    // Load this lane's 16 weights (4 x float4), reused for all batches.
    const float4* w4 = reinterpret_cast<const float4*>(w + (size_t)n * (KH * KW));
    float4 wreg[4];
#pragma unroll
    for (int j = 0; j < 4; ++j)
        wreg[j] = w4[64 * j + lane];

    const int row0 = nr * SH - PH;      // top-left of window in image coords
    const int col0 = nc * SW - PW;
    const float bn = bias[n];

    // Interior windows touch rows [row0, row0+31], cols [col0, col0+31] all in-bounds.
    const bool interior = (nr >= 1) && (nr <= 30) && (nc >= 1) && (nc <= 30);

    if (interior) {
        // Per-lane element offsets within the image (constant across batches).
        int koff[4];
#pragma unroll
        for (int j = 0; j < 4; ++j) {
            const int k = 256 * j + 4 * lane;
            koff[j] = (k >> 5) * IMG_W + (k & 31);
        }
        const size_t base0 = (size_t)row0 * IMG_W + col0;

#pragma unroll
        for (int i = 0; i < TB / 4; ++i) {
            const int b = b0 + wv + 4 * i;
            const float* xb = x + (size_t)b * (IMG_H * IMG_W) + base0;
            float s = 0.f;
#pragma unroll
            for (int j = 0; j < 4; ++j) {
                const float4 xv = *reinterpret_cast<const float4*>(xb + koff[j]);
                s = fmaf(xv.x, wreg[j].x, s);
                s = fmaf(xv.y, wreg[j].y, s);
                s = fmaf(xv.z, wreg[j].z, s);
                s = fmaf(xv.w, wreg[j].w, s);
            }
            // Wave-level butterfly reduction (64 lanes).
#pragma unroll
            for (int off = 32; off > 0; off >>= 1)
                s += __shfl_xor(s, off, 64);
            if (lane == 0)
                out[(size_t)b * NK + n] = s + bn;
        }
    } else {
        // Border positions: scalar loads with bounds checks (zero padding).
#pragma unroll
        for (int i = 0; i < TB / 4; ++i) {
            const int b = b0 + wv + 4 * i;
            const float* xb = x + (size_t)b * (IMG_H * IMG_W);
            float s = 0.f;
#pragma unroll
            for (int j = 0; j < 4; ++j) {
                const int k = 256 * j + 4 * lane;
                const int r = row0 + (k >> 5);
                const int cb = col0 + (k & 31);
                const float* wj = reinterpret_cast<const float*>(&wreg[j]);
                if (r >= 0 && r < IMG_H) {
#pragma unroll
                    for (int e = 0; e < 4; ++e) {
                        const int c = cb + e;
                        const float xv = (c >= 0 && c < IMG_W) ? xb[r * IMG_W + c] : 0.f;
                        s = fmaf(xv, wj[e], s);
                    }
                }
            }
#pragma unroll
            for (int off = 32; off > 0; off >>= 1)
                s += __shfl_xor(s, off, 64);
            if (lane == 0)
                out[(size_t)b * NK + n] = s + bn;
        }
    }
}

extern "C" void kernel_launch(void* const* d_in, const int* in_sizes, int n_in,
                              void* d_out, int out_size, void* d_ws, size_t ws_size,
                              hipStream_t stream) {
    const float* x    = (const float*)d_in[0];  // (64,1,512,512) fp32
    const float* wgt  = (const float*)d_in[1];  // (1024,1024) fp32
    const float* bias = (const float*)d_in[2];  // (1024,) fp32
    float* out        = (float*)d_out;          // (64,32,32) fp32

    dim3 grid(NK, BATCH / TB);   // (1024, 4)
    dim3 block(256);
    bslc_kernel<<<grid, block, 0, stream>>>(x, wgt, bias, out);
}

// Round 2
// 118.231 us; speedup vs baseline: 1.1945x; 1.1945x over previous
//
#include <hip/hip_runtime.h>

// Problem constants
#define IMG_H 512
#define IMG_W 512
#define NKH 32
#define NKW 32
#define NK (NKH * NKW)   // 1024 windows
#define BATCH 64
#define NT 33            // 16x16 tiles per dim of the 528x528 padded image

// Tile decomposition: padded image = 33x33 tiles of 16x16 (exact).
// Tile (tr,tc) is quadrant (qr,qc) of window (tr-qr, tc-qc), qr,qc in {0,1}.
// (window n, quadrant q) <-> tile is bijective, so each partial[b][n][q] is
// written exactly once -> no atomics, no zero-init of workspace needed.
//
// Block = one tile x one batch-group of 32. 4 waves; wave wv handles batches
// bg*32 + wv + 4*i, i=0..7. Lane l covers tile row r=l>>2, cols (l&3)*4..+3
// (one float4). Weights: 4 quadrant float4s per lane, register-resident.
__global__ __launch_bounds__(256)
void bslc_tile_kernel(const float* __restrict__ x,
                      const float* __restrict__ w,
                      float* __restrict__ partial)
{
    const int tc = blockIdx.x;          // 0..32
    const int tr = blockIdx.y;          // 0..32
    const int bg = blockIdx.z;          // 0..1
    const int lane = threadIdx.x & 63;
    const int wv   = threadIdx.x >> 6;

    const int r  = lane >> 2;           // tile row 0..15
    const int c0 = (lane & 3) * 4;      // tile col {0,4,8,12}

    // Load per-lane weight fragments for the 4 quadrants (once per block).
    float4 wreg[4];
#pragma unroll
    for (int q = 0; q < 4; ++q) {
        const int qr = q >> 1, qc = q & 1;
        const int nr = tr - qr, nc = tc - qc;
        if (nr >= 0 && nr < NKH && nc >= 0 && nc < NKW) {
            const size_t off = (size_t)(nr * NKW + nc) * 1024
                             + (size_t)(qr * 16 + r) * 32 + qc * 16 + c0;
            wreg[q] = *reinterpret_cast<const float4*>(w + off);
        } else {
            wreg[q] = make_float4(0.f, 0.f, 0.f, 0.f);
        }
    }

    // This lane's x location (image coords; padded coords minus 8).
    const int rimg = tr * 16 - 8 + r;
    const int cimg = tc * 16 - 8 + c0;
    const bool interior = (tr >= 1) && (tr <= 31) && (tc >= 1) && (tc <= 31);
    const size_t xoff = (size_t)rimg * IMG_W + cimg;

#pragma unroll
    for (int i = 0; i < 8; ++i) {
        const int b = bg * 32 + wv + 4 * i;
        const float* xb = x + (size_t)b * (IMG_H * IMG_W);

        float4 xv;
        if (interior) {
            xv = *reinterpret_cast<const float4*>(xb + xoff);
        } else {
            xv = make_float4(0.f, 0.f, 0.f, 0.f);
            if (rimg >= 0 && rimg < IMG_H) {
#pragma unroll
                for (int e = 0; e < 4; ++e) {
                    const int c = cimg + e;
                    if (c >= 0 && c < IMG_W)
                        (&xv.x)[e] = xb[(size_t)rimg * IMG_W + c];
                }
            }
        }

        // 4 quadrant partial dots (per-lane, 4 elems each).
        float s[4];
#pragma unroll
        for (int q = 0; q < 4; ++q) {
            float t;
            t = fmaf(xv.x, wreg[q].x, 0.f);
            t = fmaf(xv.y, wreg[q].y, t);
            t = fmaf(xv.z, wreg[q].z, t);
            t = fmaf(xv.w, wreg[q].w, t);
            s[q] = t;
        }

        // Wave-wide butterfly; afterwards every lane holds all 4 totals.
#pragma unroll
        for (int off = 32; off > 0; off >>= 1) {
#pragma unroll
            for (int q = 0; q < 4; ++q)
                s[q] += __shfl_xor(s[q], off, 64);
        }

        // Lane q (0..3) writes quadrant q's partial (compile-time s indices).
        if (lane < 4) {
            const int qr = lane >> 1, qc = lane & 1;
            const int nr = tr - qr, nc = tc - qc;
            if (nr >= 0 && nr < NKH && nc >= 0 && nc < NKW) {
                const float sv = (lane == 0) ? s[0]
                               : (lane == 1) ? s[1]
                               : (lane == 2) ? s[2] : s[3];
                partial[((size_t)b * NK + (nr * NKW + nc)) * 4 + lane] = sv;
            }
        }
    }
}

// out[b,n] = bias[n] + sum of the 4 quadrant partials.
__global__ __launch_bounds__(256)
void bslc_reduce_kernel(const float* __restrict__ partial,
                        const float* __restrict__ bias,
                        float* __restrict__ out)
{
    const int idx = blockIdx.x * 256 + threadIdx.x;   // b*1024 + n, 0..65535
    const int n = idx & (NK - 1);
    const float4 p = reinterpret_cast<const float4*>(partial)[idx];
    out[idx] = p.x + p.y + p.z + p.w + bias[n];
}

extern "C" void kernel_launch(void* const* d_in, const int* in_sizes, int n_in,
                              void* d_out, int out_size, void* d_ws, size_t ws_size,
                              hipStream_t stream) {
    const float* x    = (const float*)d_in[0];  // (64,1,512,512) fp32
    const float* wgt  = (const float*)d_in[1];  // (1024,1024) fp32
    const float* bias = (const float*)d_in[2];  // (1024,) fp32
    float* out        = (float*)d_out;          // (64,32,32) fp32
    float* partial    = (float*)d_ws;           // 64*1024*4 floats = 1 MiB

    dim3 grid1(NT, NT, 2);
    bslc_tile_kernel<<<grid1, 256, 0, stream>>>(x, wgt, partial);

    dim3 grid2((BATCH * NK) / 256);
    bslc_reduce_kernel<<<grid2, 256, 0, stream>>>(partial, bias, out);
}